// Round 1
// baseline (183.256 us; speedup 1.0000x reference)
//
#include <hip/hip_runtime.h>
#include <math.h>

// DeformConv2dPack on MI355X (gfx950)
// B=8, C=256, H=W=64, Cout=256, K=3x3 (9 taps), stride=1, pad=1, dil=1
//
// Pipeline:
//  P1 transpose_nhwc : x NCHW -> NHWC fp32 in ws        (33.5 MB)
//  P2 pack_w         : weight (O,C,3,3) -> bf16 [k][c/8][o][8]
//  P3 pack_wom       : w_offset+w_mask -> bf16 [k][c/8][32 rows][8] (rows 27..31 zero)
//  K1 offset_conv    : MFMA GEMM M=32(27 used) x N=64px x K=2304 -> dy/dx/mask planes fp32
//  K2 deform_gemm    : per block: 1 image-row (64 px) x all 256 out ch;
//                      bilinear-gather -> bf16 LDS tile -> mfma_f32_16x16x32_bf16
//
// ws layout (requires ~38.5 MB):
//  [0)            x_nhwc fp32   33,554,432 B
//  [33554432)     Wpack  bf16    1,179,648 B
//  [34734080)     Womp   bf16      147,456 B
//  [34881536)     dy     fp32    1,179,648 B
//  [36061184)     dx     fp32    1,179,648 B
//  [37240832)     mask   fp32    1,179,648 B   (end 38,420,480)

typedef __bf16 bf16x8 __attribute__((ext_vector_type(8)));
typedef float  f32x4  __attribute__((ext_vector_type(4)));
typedef unsigned short u16x8 __attribute__((ext_vector_type(8)));

__global__ __launch_bounds__(256) void transpose_nhwc(const float* __restrict__ x,
                                                      float* __restrict__ xt) {
  __shared__ float tile[64][65];
  const int bid = blockIdx.x;
  const int b = bid >> 8, cc = (bid >> 6) & 3, hw0 = (bid & 63) << 6;
  const int t = threadIdx.x;
  const int a = t & 63, g = t >> 6;
#pragma unroll
  for (int r = 0; r < 16; ++r) {
    int crow = (r << 2) + g;
    tile[crow][a] = x[(((b << 8) + (cc << 6) + crow) << 12) + hw0 + a];
  }
  __syncthreads();
#pragma unroll
  for (int r = 0; r < 16; ++r) {
    int hwr = (r << 2) + g;
    xt[((b << 12) + hw0 + hwr) * 256 + (cc << 6) + a] = tile[a][hwr];
  }
}

__global__ __launch_bounds__(256) void pack_w(const float* __restrict__ w,
                                              __bf16* __restrict__ wp) {
  int idx = blockIdx.x * 256 + threadIdx.x;
  if (idx >= 256 * 256 * 9) return;
  int o = idx / 2304, rem = idx - o * 2304;
  int c = rem / 9, k = rem - c * 9;
  wp[(((k << 5) + (c >> 3)) * 256 + o) * 8 + (c & 7)] = (__bf16)w[idx];
}

__global__ __launch_bounds__(256) void pack_wom(const float* __restrict__ wo,
                                                const float* __restrict__ wm,
                                                __bf16* __restrict__ wp) {
  int idx = blockIdx.x * 256 + threadIdx.x;
  if (idx >= 32 * 256 * 9) return;
  int r = idx / 2304, rem = idx - r * 2304;
  int c = rem / 9, k = rem - c * 9;
  float v = 0.f;
  if (r < 18) v = wo[((r << 8) + c) * 9 + k];
  else if (r < 27) v = wm[(((r - 18) << 8) + c) * 9 + k];
  wp[(((k << 5) + (c >> 3)) * 32 + r) * 8 + (c & 7)] = (__bf16)v;
}

// K1: offset/mask conv. grid = 8*64 (b, h-row), 256 threads (4 waves).
// M=32 rows (0..17 offset ch, 18..26 mask ch), N=64 pixels, K=2304.
__global__ __launch_bounds__(256) void offset_conv(
    const float* __restrict__ xt, const __bf16* __restrict__ wp,
    const float* __restrict__ b_off, const float* __restrict__ b_msk,
    float* __restrict__ dyp, float* __restrict__ dxp, float* __restrict__ mkp) {
  const int bi = blockIdx.x >> 6, h = blockIdx.x & 63;
  const int t = threadIdx.x, lane = t & 63, nw = t >> 6;
  const int l16 = lane & 15, lh = lane >> 4;
  __shared__ __align__(16) unsigned short S[64 * 72];  // [px][72] stride 144B
  f32x4 acc[2] = {};
  const int sp = t >> 2, sc0 = (t & 3) << 4;
  const long xb = (long)bi << 20;

  for (int k = 0; k < 9; ++k) {
    const int hh = h + k / 3 - 1;
    const int ww = sp + k % 3 - 1;
    const bool valid = (hh >= 0) & (hh < 64) & (ww >= 0) & (ww < 64);
    const float* src = xt + xb + (((hh << 6) + ww) << 8);
    for (int cc = 0; cc < 4; ++cc) {
      u16x8 pk[2] = {};
      if (valid) {
#pragma unroll
        for (int g = 0; g < 4; ++g) {
          f32x4 v = *(const f32x4*)(src + (cc << 6) + sc0 + (g << 2));
#pragma unroll
          for (int j = 0; j < 4; ++j)
            pk[g >> 1][((g & 1) << 2) + j] = __builtin_bit_cast(unsigned short, (__bf16)v[j]);
        }
      }
      __syncthreads();
      *(u16x8*)&S[sp * 72 + sc0] = pk[0];
      *(u16x8*)&S[sp * 72 + sc0 + 8] = pk[1];
      __syncthreads();
#pragma unroll
      for (int kk = 0; kk < 2; ++kk) {
        const int prow = (nw << 4) + l16;
        bf16x8 bfrag = *(const bf16x8*)&S[prow * 72 + (kk << 5) + (lh << 3)];
#pragma unroll
        for (int mf = 0; mf < 2; ++mf) {
          const __bf16* ap = wp + ((((k << 5) + (cc << 3) + (kk << 2) + lh) << 5) + (mf << 4) + l16) * 8;
          bf16x8 af = *(const bf16x8*)ap;
          acc[mf] = __builtin_amdgcn_mfma_f32_16x16x32_bf16(af, bfrag, acc[mf], 0, 0, 0);
        }
      }
    }
  }

  const int p = (nw << 4) + l16;
  const int hw = (h << 6) + p;
#pragma unroll
  for (int mf = 0; mf < 2; ++mf) {
#pragma unroll
    for (int r = 0; r < 4; ++r) {
      int row = (mf << 4) + (lh << 2) + r;
      float v = acc[mf][r];
      if (row < 18) {
        v += b_off[row];
        float* dst = (row & 1) ? dxp : dyp;
        dst[(((bi * 9) + (row >> 1)) << 12) + hw] = v;
      } else if (row < 27) {
        int km = row - 18;
        v += b_msk[km];
        mkp[(((bi * 9) + km) << 12) + hw] = 1.f / (1.f + expf(-v));
      }
    }
  }
}

// K2: fused deformable-sample + GEMM. grid = 8*64 (b, h-row), 512 threads (8 waves).
// Block tile: 256 out-ch x 64 px. Waves: 4 (M) x 2 (N). K-loop: 9 taps x 4 c-chunks of 64.
__global__ __launch_bounds__(512, 2) void deform_gemm(
    const float* __restrict__ xt, const __bf16* __restrict__ wp,
    const float* __restrict__ dyp, const float* __restrict__ dxp,
    const float* __restrict__ mkp, const float* __restrict__ bias,
    float* __restrict__ out) {
  const int bi = blockIdx.x >> 6, h = blockIdx.x & 63;
  const int t = threadIdx.x, lane = t & 63, wv = t >> 6;
  const int mw = wv >> 1, nw = wv & 1;
  const int l16 = lane & 15, lh = lane >> 4;
  __shared__ __align__(16) unsigned short S[64 * 72];  // [px][72] bf16, stride 144B
  __shared__ float offm[9][3][64];                     // [tap][dy,dx,mask][px]

  for (int i = t; i < 576; i += 512) {
    int k = i >> 6, p = i & 63;
    int idx = (((bi * 9) + k) << 12) + (h << 6) + p;
    offm[k][0][p] = dyp[idx];
    offm[k][1][p] = dxp[idx];
    offm[k][2][p] = mkp[idx];
  }
  __syncthreads();

  f32x4 acc[4][2] = {};
  const int sp = t >> 3, sc = (t & 7) << 3;  // staging: 8 thr/px, 8 ch each
  const long xb = (long)bi << 20;

  for (int k = 0; k < 9; ++k) {
    const float dy = offm[k][0][sp], dx = offm[k][1][sp], mk = offm[k][2][sp];
    const float ys = (float)(h + (k / 3) - 1) + dy;
    const float xs = (float)(sp + (k % 3) - 1) + dx;
    const float y0f = floorf(ys), x0f = floorf(xs);
    const int iy0 = (int)y0f, ix0 = (int)x0f;
    const float wy1 = ys - y0f, wx1 = xs - x0f;
    const float wy0 = 1.f - wy1, wx0 = 1.f - wx1;
    float w00 = wy0 * wx0 * mk, w01 = wy0 * wx1 * mk;
    float w10 = wy1 * wx0 * mk, w11 = wy1 * wx1 * mk;
    if (iy0 < 0 || iy0 > 63) { w00 = 0.f; w01 = 0.f; }
    if (iy0 < -1 || iy0 > 62) { w10 = 0.f; w11 = 0.f; }
    if (ix0 < 0 || ix0 > 63) { w00 = 0.f; w10 = 0.f; }
    if (ix0 < -1 || ix0 > 62) { w01 = 0.f; w11 = 0.f; }
    const int cy0 = min(max(iy0, 0), 63), cy1 = min(max(iy0 + 1, 0), 63);
    const int cx0 = min(max(ix0, 0), 63), cx1 = min(max(ix0 + 1, 0), 63);
    const float* p00 = xt + xb + (((cy0 << 6) + cx0) << 8);
    const float* p01 = xt + xb + (((cy0 << 6) + cx1) << 8);
    const float* p10 = xt + xb + (((cy1 << 6) + cx0) << 8);
    const float* p11 = xt + xb + (((cy1 << 6) + cx1) << 8);

    for (int cc = 0; cc < 4; ++cc) {
      const int c0 = (cc << 6) + sc;
      u16x8 pkv;
#pragma unroll
      for (int g = 0; g < 2; ++g) {
        f32x4 v00 = *(const f32x4*)(p00 + c0 + (g << 2));
        f32x4 v01 = *(const f32x4*)(p01 + c0 + (g << 2));
        f32x4 v10 = *(const f32x4*)(p10 + c0 + (g << 2));
        f32x4 v11 = *(const f32x4*)(p11 + c0 + (g << 2));
        f32x4 s = v00 * w00 + v01 * w01 + v10 * w10 + v11 * w11;
#pragma unroll
        for (int j = 0; j < 4; ++j)
          pkv[(g << 2) + j] = __builtin_bit_cast(unsigned short, (__bf16)s[j]);
      }
      __syncthreads();  // prior MFMA reads of S done
      *(u16x8*)&S[sp * 72 + sc] = pkv;
      __syncthreads();
#pragma unroll
      for (int kk = 0; kk < 2; ++kk) {
        bf16x8 bfrag[2];
#pragma unroll
        for (int nf = 0; nf < 2; ++nf) {
          const int prow = (nw << 5) + (nf << 4) + l16;
          bfrag[nf] = *(const bf16x8*)&S[prow * 72 + (kk << 5) + (lh << 3)];
        }
#pragma unroll
        for (int mf = 0; mf < 4; ++mf) {
          const int orow = (mw << 6) + (mf << 4) + l16;
          const __bf16* ap = wp + ((((k << 5) + (cc << 3) + (kk << 2) + lh) << 8) + orow) * 8;
          bf16x8 af = *(const bf16x8*)ap;
#pragma unroll
          for (int nf = 0; nf < 2; ++nf)
            acc[mf][nf] = __builtin_amdgcn_mfma_f32_16x16x32_bf16(af, bfrag[nf], acc[mf][nf], 0, 0, 0);
        }
      }
    }
  }

#pragma unroll
  for (int mf = 0; mf < 4; ++mf) {
    const int o = (mw << 6) + (mf << 4) + (lh << 2);
    f32x4 bv = *(const f32x4*)(bias + o);
#pragma unroll
    for (int nf = 0; nf < 2; ++nf) {
      const int p = (nw << 5) + (nf << 4) + l16;
      const int hw = (h << 6) + p;
#pragma unroll
      for (int r = 0; r < 4; ++r)
        out[(((bi << 8) + o + r) << 12) + hw] = acc[mf][nf][r] + bv[r];
    }
  }
}

extern "C" void kernel_launch(void* const* d_in, const int* in_sizes, int n_in,
                              void* d_out, int out_size, void* d_ws, size_t ws_size,
                              hipStream_t stream) {
  (void)in_sizes; (void)n_in; (void)out_size; (void)ws_size;
  const float* x        = (const float*)d_in[0];
  const float* w_offset = (const float*)d_in[1];
  const float* b_offset = (const float*)d_in[2];
  const float* w_mask   = (const float*)d_in[3];
  const float* b_mask   = (const float*)d_in[4];
  const float* weight   = (const float*)d_in[5];
  const float* bias     = (const float*)d_in[6];
  float* out = (float*)d_out;

  char* ws = (char*)d_ws;
  float*  x_nhwc = (float*)(ws);
  __bf16* Wpack  = (__bf16*)(ws + 33554432);
  __bf16* Womp   = (__bf16*)(ws + 34734080);
  float*  dyp    = (float*)(ws + 34881536);
  float*  dxp    = (float*)(ws + 36061184);
  float*  mkp    = (float*)(ws + 37240832);

  transpose_nhwc<<<2048, 256, 0, stream>>>(x, x_nhwc);
  pack_w<<<2304, 256, 0, stream>>>(weight, Wpack);
  pack_wom<<<288, 256, 0, stream>>>(w_offset, w_mask, Womp);
  offset_conv<<<512, 256, 0, stream>>>(x_nhwc, Womp, b_offset, b_mask, dyp, dxp, mkp);
  deform_gemm<<<512, 512, 0, stream>>>(x_nhwc, Wpack, dyp, dxp, mkp, bias, out);
}

// Round 2
// 135.242 us; speedup vs baseline: 1.3550x; 1.3550x over previous
//
#include <hip/hip_runtime.h>
#include <math.h>

// DeformConv2dPack on MI355X (gfx950) — v2
// B=8, C=256, H=W=64, Cout=256, K=3x3, stride=1, pad=1, dil=1
//
// v2 changes vs v1:
//  - x staged as bf16 NHWC (2.1 MB/batch): batch image + weights fit one XCD L2
//  - XCD-aware swizzle: bi = blockIdx.x & 7 -> all blocks of a batch on one XCD
//  - deform_gemm: 128-px blocks (grid 256), LDS double-buffer, ONE barrier/iter,
//    register prefetch of next chunk's corner gathers (latency hides under interp)
//  - offset_conv: same pipeline (direct bf16 copy staging, no convert)
//
// ws layout:
//  [0)          xt bf16 NHWC   16,777,216 B
//  [16777216)   Wpack bf16      1,179,648 B
//  [17956864)   Womp bf16         147,456 B
//  [18104320)   dy fp32         1,179,648 B
//  [19283968)   dx fp32         1,179,648 B
//  [20463616)   mask fp32       1,179,648 B   (end 21,643,264)

typedef __bf16 bf16x8 __attribute__((ext_vector_type(8)));
typedef float  f32x4  __attribute__((ext_vector_type(4)));
typedef unsigned short u16x8 __attribute__((ext_vector_type(8)));
typedef unsigned short u16x4 __attribute__((ext_vector_type(4)));

__device__ __forceinline__ float b2f(unsigned short u) {
  return __builtin_bit_cast(float, ((unsigned)u) << 16);
}
__device__ __forceinline__ unsigned short f2b(float f) {
  return __builtin_bit_cast(unsigned short, (__bf16)f);
}

__global__ __launch_bounds__(256) void transpose_nhwc(const float* __restrict__ x,
                                                      unsigned short* __restrict__ xt) {
  __shared__ float tile[64][65];
  const int bid = blockIdx.x;
  const int b = bid >> 8, cc = (bid >> 6) & 3, hw0 = (bid & 63) << 6;
  const int t = threadIdx.x;
  const int a = t & 63, g = t >> 6;
#pragma unroll
  for (int r = 0; r < 16; ++r) {
    int crow = (r << 2) + g;
    tile[crow][a] = x[(((b << 8) + (cc << 6) + crow) << 12) + hw0 + a];
  }
  __syncthreads();
  const int a0 = (t & 15) << 2, gg = t >> 4;
#pragma unroll
  for (int r = 0; r < 4; ++r) {
    int hwr = (r << 4) + gg;
    u16x4 v;
#pragma unroll
    for (int j = 0; j < 4; ++j) v[j] = f2b(tile[a0 + j][hwr]);
    *(u16x4*)&xt[((b << 12) + hw0 + hwr) * 256 + (cc << 6) + a0] = v;
  }
}

__global__ __launch_bounds__(256) void pack_w(const float* __restrict__ w,
                                              __bf16* __restrict__ wp) {
  int idx = blockIdx.x * 256 + threadIdx.x;
  if (idx >= 256 * 256 * 9) return;
  int o = idx / 2304, rem = idx - o * 2304;
  int c = rem / 9, k = rem - c * 9;
  wp[(((k << 5) + (c >> 3)) * 256 + o) * 8 + (c & 7)] = (__bf16)w[idx];
}

__global__ __launch_bounds__(256) void pack_wom(const float* __restrict__ wo,
                                                const float* __restrict__ wm,
                                                __bf16* __restrict__ wp) {
  int idx = blockIdx.x * 256 + threadIdx.x;
  if (idx >= 32 * 256 * 9) return;
  int r = idx / 2304, rem = idx - r * 2304;
  int c = rem / 9, k = rem - c * 9;
  float v = 0.f;
  if (r < 18) v = wo[((r << 8) + c) * 9 + k];
  else if (r < 27) v = wm[(((r - 18) << 8) + c) * 9 + k];
  wp[(((k << 5) + (c >> 3)) * 32 + r) * 8 + (c & 7)] = (__bf16)v;
}

// K1: offset/mask conv. grid = 512 (bi = bid&7 XCD-swizzled, h = bid>>3), 256 thr.
__global__ __launch_bounds__(256) void offset_conv(
    const unsigned short* __restrict__ xt, const __bf16* __restrict__ wp,
    const float* __restrict__ b_off, const float* __restrict__ b_msk,
    float* __restrict__ dyp, float* __restrict__ dxp, float* __restrict__ mkp) {
  const int bi = blockIdx.x & 7, h = blockIdx.x >> 3;
  const int t = threadIdx.x, lane = t & 63, nw = t >> 6;
  const int l16 = lane & 15, lh = lane >> 4;
  __shared__ __align__(16) unsigned short S[2][64 * 72];
  f32x4 acc[2] = {};
  const int sp = t >> 2, sc0 = (t & 3) << 4;
  const long xb = (long)bi << 20;

  auto LOAD = [&](int it, u16x8* r) {
    const int k = it >> 2, cc = it & 3;
    const int hh = h + k / 3 - 1;
    const int ww = sp + k % 3 - 1;
    const bool valid = (hh >= 0) & (hh < 64) & (ww >= 0) & (ww < 64);
    if (valid) {
      const unsigned short* src = xt + xb + (((hh << 6) + ww) << 8) + (cc << 6) + sc0;
      r[0] = *(const u16x8*)src;
      r[1] = *(const u16x8*)(src + 8);
    } else {
      r[0] = u16x8{}; r[1] = u16x8{};
    }
  };

  auto STEP = [&](int it, const u16x8* r, int buf) {
    unsigned short* Sb = S[buf];
    *(u16x8*)&Sb[sp * 72 + sc0] = r[0];
    *(u16x8*)&Sb[sp * 72 + sc0 + 8] = r[1];
    __syncthreads();
    const int k = it >> 2, cc = it & 3;
#pragma unroll
    for (int kk = 0; kk < 2; ++kk) {
      const int prow = (nw << 4) + l16;
      bf16x8 bfrag = *(const bf16x8*)&Sb[prow * 72 + (kk << 5) + (lh << 3)];
#pragma unroll
      for (int mf = 0; mf < 2; ++mf) {
        const __bf16* ap = wp + ((((k << 5) + (cc << 3) + (kk << 2) + lh) << 5) + (mf << 4) + l16) * 8;
        bf16x8 af = *(const bf16x8*)ap;
        acc[mf] = __builtin_amdgcn_mfma_f32_16x16x32_bf16(af, bfrag, acc[mf], 0, 0, 0);
      }
    }
  };

  u16x8 rA[2], rB[2];
  LOAD(0, rA);
  for (int it = 0; it < 36; it += 2) {
    LOAD(it + 1, rB);
    STEP(it, rA, 0);
    if (it + 2 < 36) LOAD(it + 2, rA);
    STEP(it + 1, rB, 1);
  }

  const int p = (nw << 4) + l16;
  const int hw = (h << 6) + p;
#pragma unroll
  for (int mf = 0; mf < 2; ++mf) {
#pragma unroll
    for (int r = 0; r < 4; ++r) {
      int row = (mf << 4) + (lh << 2) + r;
      float v = acc[mf][r];
      if (row < 18) {
        v += b_off[row];
        float* dst = (row & 1) ? dxp : dyp;
        dst[(((bi * 9) + (row >> 1)) << 12) + hw] = v;
      } else if (row < 27) {
        int km = row - 18;
        v += b_msk[km];
        mkp[(((bi * 9) + km) << 12) + hw] = 1.f / (1.f + expf(-v));
      }
    }
  }
}

// K2: fused deformable-sample + GEMM. grid = 256 (bi = bid&7, hb = bid>>3 -> 2 rows),
// 512 threads (8 waves: 4 M x 2 N). Tile: 256 out-ch x 128 px. K: 9 taps x 4 chunks of 64.
__global__ __launch_bounds__(512) void deform_gemm(
    const unsigned short* __restrict__ xt, const __bf16* __restrict__ wp,
    const float* __restrict__ dyp, const float* __restrict__ dxp,
    const float* __restrict__ mkp, const float* __restrict__ bias,
    float* __restrict__ out) {
  const int bi = blockIdx.x & 7, hb = blockIdx.x >> 3;
  const int h0 = hb << 1;
  const int t = threadIdx.x, lane = t & 63, wv = t >> 6;
  const int mw = wv >> 1, nw = wv & 1;
  const int l16 = lane & 15, lh = lane >> 4;
  __shared__ __align__(16) unsigned short S[2][128 * 72];
  __shared__ float offm[9][3][128];

  for (int i = t; i < 9 * 128; i += 512) {
    int k = i >> 7, p = i & 127;
    int idx = (((bi * 9) + k) << 12) + (h0 << 6) + p;
    offm[k][0][p] = dyp[idx];
    offm[k][1][p] = dxp[idx];
    offm[k][2][p] = mkp[idx];
  }
  __syncthreads();

  f32x4 acc[4][4] = {};
  const int sp = t >> 2, sc0 = (t & 3) << 4;  // 4 thr/px, 16 ch each
  const long xb = (long)bi << 20;

  auto GATHER = [&](int it, u16x8* r, f32x4& w4) {
    const int k = it >> 2, cc = it & 3;
    const float dy = offm[k][0][sp], dx = offm[k][1][sp], mk = offm[k][2][sp];
    const float ys = (float)(h0 + (sp >> 6) + (k / 3) - 1) + dy;
    const float xs = (float)((sp & 63) + (k % 3) - 1) + dx;
    const float y0f = floorf(ys), x0f = floorf(xs);
    const int iy0 = (int)y0f, ix0 = (int)x0f;
    const float wy1 = ys - y0f, wx1 = xs - x0f;
    const float wy0 = 1.f - wy1, wx0 = 1.f - wx1;
    float w00 = wy0 * wx0 * mk, w01 = wy0 * wx1 * mk;
    float w10 = wy1 * wx0 * mk, w11 = wy1 * wx1 * mk;
    if (iy0 < 0 || iy0 > 63) { w00 = 0.f; w01 = 0.f; }
    if (iy0 < -1 || iy0 > 62) { w10 = 0.f; w11 = 0.f; }
    if (ix0 < 0 || ix0 > 63) { w00 = 0.f; w10 = 0.f; }
    if (ix0 < -1 || ix0 > 62) { w01 = 0.f; w11 = 0.f; }
    const int cy0 = min(max(iy0, 0), 63), cy1 = min(max(iy0 + 1, 0), 63);
    const int cx0 = min(max(ix0, 0), 63), cx1 = min(max(ix0 + 1, 0), 63);
    const int c0 = (cc << 6) + sc0;
    const unsigned short* b00 = xt + xb + (((cy0 << 6) + cx0) << 8) + c0;
    const unsigned short* b01 = xt + xb + (((cy0 << 6) + cx1) << 8) + c0;
    const unsigned short* b10 = xt + xb + (((cy1 << 6) + cx0) << 8) + c0;
    const unsigned short* b11 = xt + xb + (((cy1 << 6) + cx1) << 8) + c0;
    r[0] = *(const u16x8*)b00; r[1] = *(const u16x8*)(b00 + 8);
    r[2] = *(const u16x8*)b01; r[3] = *(const u16x8*)(b01 + 8);
    r[4] = *(const u16x8*)b10; r[5] = *(const u16x8*)(b10 + 8);
    r[6] = *(const u16x8*)b11; r[7] = *(const u16x8*)(b11 + 8);
    w4 = f32x4{w00, w01, w10, w11};
  };

  auto STEP = [&](int it, const u16x8* r, const f32x4& w4, int buf) {
    u16x8 sv0, sv1;
#pragma unroll
    for (int j = 0; j < 8; ++j) {
      float f0 = w4.x * b2f(r[0][j]) + w4.y * b2f(r[2][j]) + w4.z * b2f(r[4][j]) + w4.w * b2f(r[6][j]);
      float f1 = w4.x * b2f(r[1][j]) + w4.y * b2f(r[3][j]) + w4.z * b2f(r[5][j]) + w4.w * b2f(r[7][j]);
      sv0[j] = f2b(f0);
      sv1[j] = f2b(f1);
    }
    unsigned short* Sb = S[buf];
    *(u16x8*)&Sb[sp * 72 + sc0] = sv0;
    *(u16x8*)&Sb[sp * 72 + sc0 + 8] = sv1;
    __syncthreads();
    const int k = it >> 2, cc = it & 3;
#pragma unroll
    for (int kk = 0; kk < 2; ++kk) {
      bf16x8 bfr[4];
#pragma unroll
      for (int nf = 0; nf < 4; ++nf) {
        const int prow = (nw << 6) + (nf << 4) + l16;
        bfr[nf] = *(const bf16x8*)&Sb[prow * 72 + (kk << 5) + (lh << 3)];
      }
#pragma unroll
      for (int mf = 0; mf < 4; ++mf) {
        const int orow = (mw << 6) + (mf << 4) + l16;
        const __bf16* ap = wp + ((((k << 5) + (cc << 3) + (kk << 2) + lh) << 8) + orow) * 8;
        bf16x8 af = *(const bf16x8*)ap;
#pragma unroll
        for (int nf = 0; nf < 4; ++nf)
          acc[mf][nf] = __builtin_amdgcn_mfma_f32_16x16x32_bf16(af, bfr[nf], acc[mf][nf], 0, 0, 0);
      }
    }
  };

  u16x8 rA[8], rB[8];
  f32x4 wA, wB;
  GATHER(0, rA, wA);
  for (int it = 0; it < 36; it += 2) {
    GATHER(it + 1, rB, wB);
    STEP(it, rA, wA, 0);
    if (it + 2 < 36) GATHER(it + 2, rA, wA);
    STEP(it + 1, rB, wB, 1);
  }

#pragma unroll
  for (int mf = 0; mf < 4; ++mf) {
    const int o = (mw << 6) + (mf << 4) + (lh << 2);
    f32x4 bv = *(const f32x4*)(bias + o);
#pragma unroll
    for (int nf = 0; nf < 4; ++nf) {
      const int p = (nw << 6) + (nf << 4) + l16;
      const int hw = (h0 << 6) + p;
#pragma unroll
      for (int r = 0; r < 4; ++r)
        out[(((bi << 8) + o + r) << 12) + hw] = acc[mf][nf][r] + bv[r];
    }
  }
}

extern "C" void kernel_launch(void* const* d_in, const int* in_sizes, int n_in,
                              void* d_out, int out_size, void* d_ws, size_t ws_size,
                              hipStream_t stream) {
  (void)in_sizes; (void)n_in; (void)out_size; (void)ws_size;
  const float* x        = (const float*)d_in[0];
  const float* w_offset = (const float*)d_in[1];
  const float* b_offset = (const float*)d_in[2];
  const float* w_mask   = (const float*)d_in[3];
  const float* b_mask   = (const float*)d_in[4];
  const float* weight   = (const float*)d_in[5];
  const float* bias     = (const float*)d_in[6];
  float* out = (float*)d_out;

  char* ws = (char*)d_ws;
  unsigned short* xt = (unsigned short*)(ws);
  __bf16* Wpack  = (__bf16*)(ws + 16777216);
  __bf16* Womp   = (__bf16*)(ws + 17956864);
  float*  dyp    = (float*)(ws + 18104320);
  float*  dxp    = (float*)(ws + 19283968);
  float*  mkp    = (float*)(ws + 20463616);

  transpose_nhwc<<<2048, 256, 0, stream>>>(x, xt);
  pack_w<<<2304, 256, 0, stream>>>(weight, Wpack);
  pack_wom<<<288, 256, 0, stream>>>(w_offset, w_mask, Womp);
  offset_conv<<<512, 256, 0, stream>>>(xt, Womp, b_offset, b_mask, dyp, dxp, mkp);
  deform_gemm<<<256, 512, 0, stream>>>(xt, Wpack, dyp, dxp, mkp, bias, out);
}

// Round 3
// 119.689 us; speedup vs baseline: 1.5311x; 1.1299x over previous
//
#include <hip/hip_runtime.h>
#include <math.h>

// DeformConv2dPack on MI355X (gfx950) — v3
// B=8, C=256, H=W=64, Cout=256, K=3x3, stride=1, pad=1, dil=1
//
// v3 changes vs v2 (deform_gemm):
//  - 256out x 64px tiles, 512 thr (8 waves, each owning a 32-row M slice, nw=1)
//    -> grid 512, 2 blocks/CU, 50% occupancy target, AND no duplicated
//       weight-fragment reads (each A frag read exactly once per block)
//  - LDS 25.3 KB/block (dbuf S + offm)
//
// ws layout:
//  [0)          xt bf16 NHWC   16,777,216 B
//  [16777216)   Wpack bf16      1,179,648 B
//  [17956864)   Womp bf16         147,456 B
//  [18104320)   dy fp32         1,179,648 B
//  [19283968)   dx fp32         1,179,648 B
//  [20463616)   mask fp32       1,179,648 B   (end 21,643,264)

typedef __bf16 bf16x8 __attribute__((ext_vector_type(8)));
typedef float  f32x4  __attribute__((ext_vector_type(4)));
typedef unsigned short u16x8 __attribute__((ext_vector_type(8)));
typedef unsigned short u16x4 __attribute__((ext_vector_type(4)));

__device__ __forceinline__ float b2f(unsigned short u) {
  return __builtin_bit_cast(float, ((unsigned)u) << 16);
}
__device__ __forceinline__ unsigned short f2b(float f) {
  return __builtin_bit_cast(unsigned short, (__bf16)f);
}

__global__ __launch_bounds__(256) void transpose_nhwc(const float* __restrict__ x,
                                                      unsigned short* __restrict__ xt) {
  __shared__ float tile[64][65];
  const int bid = blockIdx.x;
  const int b = bid >> 8, cc = (bid >> 6) & 3, hw0 = (bid & 63) << 6;
  const int t = threadIdx.x;
  const int a = t & 63, g = t >> 6;
#pragma unroll
  for (int r = 0; r < 16; ++r) {
    int crow = (r << 2) + g;
    tile[crow][a] = x[(((b << 8) + (cc << 6) + crow) << 12) + hw0 + a];
  }
  __syncthreads();
  const int a0 = (t & 15) << 2, gg = t >> 4;
#pragma unroll
  for (int r = 0; r < 4; ++r) {
    int hwr = (r << 4) + gg;
    u16x4 v;
#pragma unroll
    for (int j = 0; j < 4; ++j) v[j] = f2b(tile[a0 + j][hwr]);
    *(u16x4*)&xt[((b << 12) + hw0 + hwr) * 256 + (cc << 6) + a0] = v;
  }
}

__global__ __launch_bounds__(256) void pack_w(const float* __restrict__ w,
                                              __bf16* __restrict__ wp) {
  int idx = blockIdx.x * 256 + threadIdx.x;
  if (idx >= 256 * 256 * 9) return;
  int o = idx / 2304, rem = idx - o * 2304;
  int c = rem / 9, k = rem - c * 9;
  wp[(((k << 5) + (c >> 3)) * 256 + o) * 8 + (c & 7)] = (__bf16)w[idx];
}

__global__ __launch_bounds__(256) void pack_wom(const float* __restrict__ wo,
                                                const float* __restrict__ wm,
                                                __bf16* __restrict__ wp) {
  int idx = blockIdx.x * 256 + threadIdx.x;
  if (idx >= 32 * 256 * 9) return;
  int r = idx / 2304, rem = idx - r * 2304;
  int c = rem / 9, k = rem - c * 9;
  float v = 0.f;
  if (r < 18) v = wo[((r << 8) + c) * 9 + k];
  else if (r < 27) v = wm[(((r - 18) << 8) + c) * 9 + k];
  wp[(((k << 5) + (c >> 3)) * 32 + r) * 8 + (c & 7)] = (__bf16)v;
}

// K1: offset/mask conv. grid = 512 (bi = bid&7 XCD-swizzled, h = bid>>3), 256 thr.
__global__ __launch_bounds__(256) void offset_conv(
    const unsigned short* __restrict__ xt, const __bf16* __restrict__ wp,
    const float* __restrict__ b_off, const float* __restrict__ b_msk,
    float* __restrict__ dyp, float* __restrict__ dxp, float* __restrict__ mkp) {
  const int bi = blockIdx.x & 7, h = blockIdx.x >> 3;
  const int t = threadIdx.x, lane = t & 63, nw = t >> 6;
  const int l16 = lane & 15, lh = lane >> 4;
  __shared__ __align__(16) unsigned short S[2][64 * 72];
  f32x4 acc[2] = {};
  const int sp = t >> 2, sc0 = (t & 3) << 4;
  const long xb = (long)bi << 20;

  auto LOAD = [&](int it, u16x8* r) {
    const int k = it >> 2, cc = it & 3;
    const int hh = h + k / 3 - 1;
    const int ww = sp + k % 3 - 1;
    const bool valid = (hh >= 0) & (hh < 64) & (ww >= 0) & (ww < 64);
    if (valid) {
      const unsigned short* src = xt + xb + (((hh << 6) + ww) << 8) + (cc << 6) + sc0;
      r[0] = *(const u16x8*)src;
      r[1] = *(const u16x8*)(src + 8);
    } else {
      r[0] = u16x8{}; r[1] = u16x8{};
    }
  };

  auto STEP = [&](int it, const u16x8* r, int buf) {
    unsigned short* Sb = S[buf];
    *(u16x8*)&Sb[sp * 72 + sc0] = r[0];
    *(u16x8*)&Sb[sp * 72 + sc0 + 8] = r[1];
    __syncthreads();
    const int k = it >> 2, cc = it & 3;
#pragma unroll
    for (int kk = 0; kk < 2; ++kk) {
      const int prow = (nw << 4) + l16;
      bf16x8 bfrag = *(const bf16x8*)&Sb[prow * 72 + (kk << 5) + (lh << 3)];
#pragma unroll
      for (int mf = 0; mf < 2; ++mf) {
        const __bf16* ap = wp + ((((k << 5) + (cc << 3) + (kk << 2) + lh) << 5) + (mf << 4) + l16) * 8;
        bf16x8 af = *(const bf16x8*)ap;
        acc[mf] = __builtin_amdgcn_mfma_f32_16x16x32_bf16(af, bfrag, acc[mf], 0, 0, 0);
      }
    }
  };

  u16x8 rA[2], rB[2];
  LOAD(0, rA);
  for (int it = 0; it < 36; it += 2) {
    LOAD(it + 1, rB);
    STEP(it, rA, 0);
    if (it + 2 < 36) LOAD(it + 2, rA);
    STEP(it + 1, rB, 1);
  }

  const int p = (nw << 4) + l16;
  const int hw = (h << 6) + p;
#pragma unroll
  for (int mf = 0; mf < 2; ++mf) {
#pragma unroll
    for (int r = 0; r < 4; ++r) {
      int row = (mf << 4) + (lh << 2) + r;
      float v = acc[mf][r];
      if (row < 18) {
        v += b_off[row];
        float* dst = (row & 1) ? dxp : dyp;
        dst[(((bi * 9) + (row >> 1)) << 12) + hw] = v;
      } else if (row < 27) {
        int km = row - 18;
        v += b_msk[km];
        mkp[(((bi * 9) + km) << 12) + hw] = 1.f / (1.f + expf(-v));
      }
    }
  }
}

// K2: fused deformable-sample + GEMM. grid = 512 (bi = bid&7, h = bid>>3),
// 512 threads = 8 waves; wave wv owns out rows [wv*32, wv*32+32). Tile 256out x 64px.
// K-loop: 9 taps x 4 c-chunks of 64. No duplicated weight reads (nw=1).
__global__ __launch_bounds__(512, 4) void deform_gemm(
    const unsigned short* __restrict__ xt, const __bf16* __restrict__ wp,
    const float* __restrict__ dyp, const float* __restrict__ dxp,
    const float* __restrict__ mkp, const float* __restrict__ bias,
    float* __restrict__ out) {
  const int bi = blockIdx.x & 7, h = blockIdx.x >> 3;
  const int t = threadIdx.x, lane = t & 63, wv = t >> 6;
  const int l16 = lane & 15, lh = lane >> 4;
  __shared__ __align__(16) unsigned short S[2][64 * 72];
  __shared__ float offm[9][3][64];

  for (int i = t; i < 9 * 3 * 64; i += 512) {
    int k = i / 192, rem = i - k * 192;
    int comp = rem >> 6, p = rem & 63;
    int idx = (((bi * 9) + k) << 12) + (h << 6) + p;
    const float* src = (comp == 0) ? dyp : (comp == 1) ? dxp : mkp;
    offm[k][comp][p] = src[idx];
  }
  __syncthreads();

  f32x4 acc[2][4] = {};
  const int sp = t >> 3, sc0 = (t & 7) << 3;  // 8 thr/px, 8 ch each
  const long xb = (long)bi << 20;

  auto GATHER = [&](int it, u16x8* r, f32x4& w4) {
    const int k = it >> 2, cc = it & 3;
    const float dy = offm[k][0][sp], dx = offm[k][1][sp], mk = offm[k][2][sp];
    const float ys = (float)(h + (k / 3) - 1) + dy;
    const float xs = (float)(sp + (k % 3) - 1) + dx;
    const float y0f = floorf(ys), x0f = floorf(xs);
    const int iy0 = (int)y0f, ix0 = (int)x0f;
    const float wy1 = ys - y0f, wx1 = xs - x0f;
    const float wy0 = 1.f - wy1, wx0 = 1.f - wx1;
    float w00 = wy0 * wx0 * mk, w01 = wy0 * wx1 * mk;
    float w10 = wy1 * wx0 * mk, w11 = wy1 * wx1 * mk;
    if (iy0 < 0 || iy0 > 63) { w00 = 0.f; w01 = 0.f; }
    if (iy0 < -1 || iy0 > 62) { w10 = 0.f; w11 = 0.f; }
    if (ix0 < 0 || ix0 > 63) { w00 = 0.f; w10 = 0.f; }
    if (ix0 < -1 || ix0 > 62) { w01 = 0.f; w11 = 0.f; }
    const int cy0 = min(max(iy0, 0), 63), cy1 = min(max(iy0 + 1, 0), 63);
    const int cx0 = min(max(ix0, 0), 63), cx1 = min(max(ix0 + 1, 0), 63);
    const int c0 = (cc << 6) + sc0;
    r[0] = *(const u16x8*)(xt + xb + (((cy0 << 6) + cx0) << 8) + c0);
    r[1] = *(const u16x8*)(xt + xb + (((cy0 << 6) + cx1) << 8) + c0);
    r[2] = *(const u16x8*)(xt + xb + (((cy1 << 6) + cx0) << 8) + c0);
    r[3] = *(const u16x8*)(xt + xb + (((cy1 << 6) + cx1) << 8) + c0);
    w4 = f32x4{w00, w01, w10, w11};
  };

  auto STEP = [&](int it, const u16x8* r, const f32x4& w4, int buf) {
    u16x8 sv;
#pragma unroll
    for (int j = 0; j < 8; ++j) {
      float f = w4.x * b2f(r[0][j]) + w4.y * b2f(r[1][j]) +
                w4.z * b2f(r[2][j]) + w4.w * b2f(r[3][j]);
      sv[j] = f2b(f);
    }
    unsigned short* Sb = S[buf];
    *(u16x8*)&Sb[sp * 72 + sc0] = sv;
    __syncthreads();
    const int k = it >> 2, cc = it & 3;
#pragma unroll
    for (int kk = 0; kk < 2; ++kk) {
      bf16x8 bfr[4];
#pragma unroll
      for (int nf = 0; nf < 4; ++nf) {
        const int prow = (nf << 4) + l16;
        bfr[nf] = *(const bf16x8*)&Sb[prow * 72 + (kk << 5) + (lh << 3)];
      }
#pragma unroll
      for (int mf = 0; mf < 2; ++mf) {
        const int orow = (wv << 5) + (mf << 4) + l16;
        const __bf16* ap = wp + ((((k << 5) + (cc << 3) + (kk << 2) + lh) << 8) + orow) * 8;
        bf16x8 af = *(const bf16x8*)ap;
#pragma unroll
        for (int nf = 0; nf < 4; ++nf)
          acc[mf][nf] = __builtin_amdgcn_mfma_f32_16x16x32_bf16(af, bfr[nf], acc[mf][nf], 0, 0, 0);
      }
    }
  };

  u16x8 rA[4], rB[4];
  f32x4 wA, wB;
  GATHER(0, rA, wA);
  for (int it = 0; it < 36; it += 2) {
    GATHER(it + 1, rB, wB);
    STEP(it, rA, wA, 0);
    if (it + 2 < 36) GATHER(it + 2, rA, wA);
    STEP(it + 1, rB, wB, 1);
  }

#pragma unroll
  for (int mf = 0; mf < 2; ++mf) {
    const int o = (wv << 5) + (mf << 4) + (lh << 2);
    f32x4 bv = *(const f32x4*)(bias + o);
#pragma unroll
    for (int nf = 0; nf < 4; ++nf) {
      const int p = (nf << 4) + l16;
      const int hw = (h << 6) + p;
#pragma unroll
      for (int r = 0; r < 4; ++r)
        out[(((bi << 8) + o + r) << 12) + hw] = acc[mf][nf][r] + bv[r];
    }
  }
}

extern "C" void kernel_launch(void* const* d_in, const int* in_sizes, int n_in,
                              void* d_out, int out_size, void* d_ws, size_t ws_size,
                              hipStream_t stream) {
  (void)in_sizes; (void)n_in; (void)out_size; (void)ws_size;
  const float* x        = (const float*)d_in[0];
  const float* w_offset = (const float*)d_in[1];
  const float* b_offset = (const float*)d_in[2];
  const float* w_mask   = (const float*)d_in[3];
  const float* b_mask   = (const float*)d_in[4];
  const float* weight   = (const float*)d_in[5];
  const float* bias     = (const float*)d_in[6];
  float* out = (float*)d_out;

  char* ws = (char*)d_ws;
  unsigned short* xt = (unsigned short*)(ws);
  __bf16* Wpack  = (__bf16*)(ws + 16777216);
  __bf16* Womp   = (__bf16*)(ws + 17956864);
  float*  dyp    = (float*)(ws + 18104320);
  float*  dxp    = (float*)(ws + 19283968);
  float*  mkp    = (float*)(ws + 20463616);

  transpose_nhwc<<<2048, 256, 0, stream>>>(x, xt);
  pack_w<<<2304, 256, 0, stream>>>(weight, Wpack);
  pack_wom<<<288, 256, 0, stream>>>(w_offset, w_mask, Womp);
  offset_conv<<<512, 256, 0, stream>>>(xt, Womp, b_offset, b_mask, dyp, dxp, mkp);
  deform_gemm<<<512, 512, 0, stream>>>(xt, Wpack, dyp, dxp, mkp, bias, out);
}

// Round 4
// 111.473 us; speedup vs baseline: 1.6440x; 1.0737x over previous
//
#include <hip/hip_runtime.h>
#include <math.h>

// DeformConv2dPack on MI355X (gfx950) — v4
// B=8, C=256, H=W=64, Cout=256, K=3x3, stride=1, pad=1, dil=1
//
// v4 changes vs v3 (deform_gemm):
//  - per-(tap,px) sample data (4 interp weights + 4 clamped corner offsets)
//    precomputed ONCE into LDS samp[9][64][8] -> main-loop GATHER is
//    2 broadcast ds_read_b128 + 4 address adds (was ~35 VALU ops, 4x redundant)
//  - interp blend in packed f32x2 (v_pk_fma_f32) with 2-op bf16-pair unpack
//  - transpose_nhwc XCD-swizzled (batch b -> XCD b) to warm the right L2
//
// ws layout:
//  [0)          xt bf16 NHWC   16,777,216 B
//  [16777216)   Wpack bf16      1,179,648 B
//  [17956864)   Womp bf16         147,456 B
//  [18104320)   dy fp32         1,179,648 B
//  [19283968)   dx fp32         1,179,648 B
//  [20463616)   mask fp32       1,179,648 B   (end 21,643,264)

typedef __bf16 bf16x8 __attribute__((ext_vector_type(8)));
typedef float  f32x4  __attribute__((ext_vector_type(4)));
typedef float  f32x2  __attribute__((ext_vector_type(2)));
typedef int    i32x4  __attribute__((ext_vector_type(4)));
typedef unsigned short u16x8 __attribute__((ext_vector_type(8)));
typedef unsigned short u16x4 __attribute__((ext_vector_type(4)));

__device__ __forceinline__ float b2f(unsigned short u) {
  return __builtin_bit_cast(float, ((unsigned)u) << 16);
}
__device__ __forceinline__ unsigned short f2b(float f) {
  return __builtin_bit_cast(unsigned short, (__bf16)f);
}
__device__ __forceinline__ float blo(unsigned u) {
  return __builtin_bit_cast(float, u << 16);
}
__device__ __forceinline__ float bhi(unsigned u) {
  return __builtin_bit_cast(float, u & 0xffff0000u);
}

__global__ __launch_bounds__(256) void transpose_nhwc(const float* __restrict__ x,
                                                      unsigned short* __restrict__ xt) {
  __shared__ float tile[64][65];
  const int bid = blockIdx.x;
  const int b = bid & 7, rem = bid >> 3;
  const int cc = rem & 3, hw0 = (rem >> 2) << 6;
  const int t = threadIdx.x;
  const int a = t & 63, g = t >> 6;
#pragma unroll
  for (int r = 0; r < 16; ++r) {
    int crow = (r << 2) + g;
    tile[crow][a] = x[(((b << 8) + (cc << 6) + crow) << 12) + hw0 + a];
  }
  __syncthreads();
  const int a0 = (t & 15) << 2, gg = t >> 4;
#pragma unroll
  for (int r = 0; r < 4; ++r) {
    int hwr = (r << 4) + gg;
    u16x4 v;
#pragma unroll
    for (int j = 0; j < 4; ++j) v[j] = f2b(tile[a0 + j][hwr]);
    *(u16x4*)&xt[((b << 12) + hw0 + hwr) * 256 + (cc << 6) + a0] = v;
  }
}

__global__ __launch_bounds__(256) void pack_w(const float* __restrict__ w,
                                              __bf16* __restrict__ wp) {
  int idx = blockIdx.x * 256 + threadIdx.x;
  if (idx >= 256 * 256 * 9) return;
  int o = idx / 2304, rem = idx - o * 2304;
  int c = rem / 9, k = rem - c * 9;
  wp[(((k << 5) + (c >> 3)) * 256 + o) * 8 + (c & 7)] = (__bf16)w[idx];
}

__global__ __launch_bounds__(256) void pack_wom(const float* __restrict__ wo,
                                                const float* __restrict__ wm,
                                                __bf16* __restrict__ wp) {
  int idx = blockIdx.x * 256 + threadIdx.x;
  if (idx >= 32 * 256 * 9) return;
  int r = idx / 2304, rem = idx - r * 2304;
  int c = rem / 9, k = rem - c * 9;
  float v = 0.f;
  if (r < 18) v = wo[((r << 8) + c) * 9 + k];
  else if (r < 27) v = wm[(((r - 18) << 8) + c) * 9 + k];
  wp[(((k << 5) + (c >> 3)) * 32 + r) * 8 + (c & 7)] = (__bf16)v;
}

// K1: offset/mask conv. grid = 512 (bi = bid&7 XCD-swizzled, h = bid>>3), 256 thr.
__global__ __launch_bounds__(256) void offset_conv(
    const unsigned short* __restrict__ xt, const __bf16* __restrict__ wp,
    const float* __restrict__ b_off, const float* __restrict__ b_msk,
    float* __restrict__ dyp, float* __restrict__ dxp, float* __restrict__ mkp) {
  const int bi = blockIdx.x & 7, h = blockIdx.x >> 3;
  const int t = threadIdx.x, lane = t & 63, nw = t >> 6;
  const int l16 = lane & 15, lh = lane >> 4;
  __shared__ __align__(16) unsigned short S[2][64 * 72];
  f32x4 acc[2] = {};
  const int sp = t >> 2, sc0 = (t & 3) << 4;
  const long xb = (long)bi << 20;

  auto LOAD = [&](int it, u16x8* r) {
    const int k = it >> 2, cc = it & 3;
    const int hh = h + k / 3 - 1;
    const int ww = sp + k % 3 - 1;
    const bool valid = (hh >= 0) & (hh < 64) & (ww >= 0) & (ww < 64);
    if (valid) {
      const unsigned short* src = xt + xb + (((hh << 6) + ww) << 8) + (cc << 6) + sc0;
      r[0] = *(const u16x8*)src;
      r[1] = *(const u16x8*)(src + 8);
    } else {
      r[0] = u16x8{}; r[1] = u16x8{};
    }
  };

  auto STEP = [&](int it, const u16x8* r, int buf) {
    unsigned short* Sb = S[buf];
    *(u16x8*)&Sb[sp * 72 + sc0] = r[0];
    *(u16x8*)&Sb[sp * 72 + sc0 + 8] = r[1];
    __syncthreads();
    const int k = it >> 2, cc = it & 3;
#pragma unroll
    for (int kk = 0; kk < 2; ++kk) {
      const int prow = (nw << 4) + l16;
      bf16x8 bfrag = *(const bf16x8*)&Sb[prow * 72 + (kk << 5) + (lh << 3)];
#pragma unroll
      for (int mf = 0; mf < 2; ++mf) {
        const __bf16* ap = wp + ((((k << 5) + (cc << 3) + (kk << 2) + lh) << 5) + (mf << 4) + l16) * 8;
        bf16x8 af = *(const bf16x8*)ap;
        acc[mf] = __builtin_amdgcn_mfma_f32_16x16x32_bf16(af, bfrag, acc[mf], 0, 0, 0);
      }
    }
  };

  u16x8 rA[2], rB[2];
  LOAD(0, rA);
  for (int it = 0; it < 36; it += 2) {
    LOAD(it + 1, rB);
    STEP(it, rA, 0);
    if (it + 2 < 36) LOAD(it + 2, rA);
    STEP(it + 1, rB, 1);
  }

  const int p = (nw << 4) + l16;
  const int hw = (h << 6) + p;
#pragma unroll
  for (int mf = 0; mf < 2; ++mf) {
#pragma unroll
    for (int r = 0; r < 4; ++r) {
      int row = (mf << 4) + (lh << 2) + r;
      float v = acc[mf][r];
      if (row < 18) {
        v += b_off[row];
        float* dst = (row & 1) ? dxp : dyp;
        dst[(((bi * 9) + (row >> 1)) << 12) + hw] = v;
      } else if (row < 27) {
        int km = row - 18;
        v += b_msk[km];
        mkp[(((bi * 9) + km) << 12) + hw] = 1.f / (1.f + expf(-v));
      }
    }
  }
}

// K2: fused deformable-sample + GEMM. grid = 512 (bi = bid&7, h = bid>>3),
// 512 threads = 8 waves; wave wv owns out rows [wv*32, wv*32+32). Tile 256out x 64px.
__global__ __launch_bounds__(512, 4) void deform_gemm(
    const unsigned short* __restrict__ xt, const __bf16* __restrict__ wp,
    const float* __restrict__ dyp, const float* __restrict__ dxp,
    const float* __restrict__ mkp, const float* __restrict__ bias,
    float* __restrict__ out) {
  const int bi = blockIdx.x & 7, h = blockIdx.x >> 3;
  const int t = threadIdx.x, lane = t & 63, wv = t >> 6;
  const int l16 = lane & 15, lh = lane >> 4;
  __shared__ __align__(16) unsigned short S[2][64 * 72];  // 18.4 KB
  __shared__ __align__(16) float samp[9][64][8];          // 18 KB: w00..w11, o00..o11

  // Precompute per-(tap,px) interp weights + clamped corner offsets (once).
  for (int i = t; i < 576; i += 512) {
    int k = i >> 6, p = i & 63;
    int idx = (((bi * 9) + k) << 12) + (h << 6) + p;
    float dy = dyp[idx], dx = dxp[idx], mk = mkp[idx];
    float ys = (float)(h + k / 3 - 1) + dy;
    float xs = (float)(p + k % 3 - 1) + dx;
    float y0f = floorf(ys), x0f = floorf(xs);
    int iy0 = (int)y0f, ix0 = (int)x0f;
    float wy1 = ys - y0f, wx1 = xs - x0f;
    float wy0 = 1.f - wy1, wx0 = 1.f - wx1;
    float w00 = wy0 * wx0 * mk, w01 = wy0 * wx1 * mk;
    float w10 = wy1 * wx0 * mk, w11 = wy1 * wx1 * mk;
    if (iy0 < 0 || iy0 > 63) { w00 = 0.f; w01 = 0.f; }
    if (iy0 < -1 || iy0 > 62) { w10 = 0.f; w11 = 0.f; }
    if (ix0 < 0 || ix0 > 63) { w00 = 0.f; w10 = 0.f; }
    if (ix0 < -1 || ix0 > 62) { w01 = 0.f; w11 = 0.f; }
    const int cy0 = min(max(iy0, 0), 63), cy1 = min(max(iy0 + 1, 0), 63);
    const int cx0 = min(max(ix0, 0), 63), cx1 = min(max(ix0 + 1, 0), 63);
    samp[k][p][0] = w00; samp[k][p][1] = w01;
    samp[k][p][2] = w10; samp[k][p][3] = w11;
    samp[k][p][4] = __builtin_bit_cast(float, (((cy0 << 6) + cx0) << 8));
    samp[k][p][5] = __builtin_bit_cast(float, (((cy0 << 6) + cx1) << 8));
    samp[k][p][6] = __builtin_bit_cast(float, (((cy1 << 6) + cx0) << 8));
    samp[k][p][7] = __builtin_bit_cast(float, (((cy1 << 6) + cx1) << 8));
  }
  __syncthreads();

  f32x4 acc[2][4] = {};
  const int sp = t >> 3, sc0 = (t & 7) << 3;  // 8 thr/px, 8 ch each
  const unsigned short* xtb = xt + ((long)bi << 20);

  auto GATHER = [&](int it, u16x8* r, f32x4& w4) {
    const int k = it >> 2, cc = it & 3;
    w4 = *(const f32x4*)&samp[k][sp][0];
    i32x4 o4 = __builtin_bit_cast(i32x4, *(const f32x4*)&samp[k][sp][4]);
    const int c0 = (cc << 6) + sc0;
    r[0] = *(const u16x8*)(xtb + o4.x + c0);
    r[1] = *(const u16x8*)(xtb + o4.y + c0);
    r[2] = *(const u16x8*)(xtb + o4.z + c0);
    r[3] = *(const u16x8*)(xtb + o4.w + c0);
  };

  auto STEP = [&](int it, const u16x8* r, const f32x4& w4, int buf) {
    u16x8 sv;
    const unsigned* u0 = (const unsigned*)&r[0];
    const unsigned* u1 = (const unsigned*)&r[1];
    const unsigned* u2 = (const unsigned*)&r[2];
    const unsigned* u3 = (const unsigned*)&r[3];
#pragma unroll
    for (int j = 0; j < 4; ++j) {
      f32x2 a{blo(u0[j]), bhi(u0[j])};
      f32x2 b{blo(u1[j]), bhi(u1[j])};
      f32x2 c{blo(u2[j]), bhi(u2[j])};
      f32x2 d{blo(u3[j]), bhi(u3[j])};
      f32x2 s = a * w4.x;
      s += b * w4.y;
      s += c * w4.z;
      s += d * w4.w;
      sv[2 * j]     = f2b(s.x);
      sv[2 * j + 1] = f2b(s.y);
    }
    unsigned short* Sb = S[buf];
    *(u16x8*)&Sb[sp * 72 + sc0] = sv;
    __syncthreads();
    const int k = it >> 2, cc = it & 3;
#pragma unroll
    for (int kk = 0; kk < 2; ++kk) {
      bf16x8 bfr[4];
#pragma unroll
      for (int nf = 0; nf < 4; ++nf) {
        const int prow = (nf << 4) + l16;
        bfr[nf] = *(const bf16x8*)&Sb[prow * 72 + (kk << 5) + (lh << 3)];
      }
#pragma unroll
      for (int mf = 0; mf < 2; ++mf) {
        const int orow = (wv << 5) + (mf << 4) + l16;
        const __bf16* ap = wp + ((((k << 5) + (cc << 3) + (kk << 2) + lh) << 8) + orow) * 8;
        bf16x8 af = *(const bf16x8*)ap;
#pragma unroll
        for (int nf = 0; nf < 4; ++nf)
          acc[mf][nf] = __builtin_amdgcn_mfma_f32_16x16x32_bf16(af, bfr[nf], acc[mf][nf], 0, 0, 0);
      }
    }
  };

  u16x8 rA[4], rB[4];
  f32x4 wA, wB;
  GATHER(0, rA, wA);
  for (int it = 0; it < 36; it += 2) {
    GATHER(it + 1, rB, wB);
    STEP(it, rA, wA, 0);
    if (it + 2 < 36) GATHER(it + 2, rA, wA);
    STEP(it + 1, rB, wB, 1);
  }

#pragma unroll
  for (int mf = 0; mf < 2; ++mf) {
    const int o = (wv << 5) + (mf << 4) + (lh << 2);
    f32x4 bv = *(const f32x4*)(bias + o);
#pragma unroll
    for (int nf = 0; nf < 4; ++nf) {
      const int p = (nf << 4) + l16;
      const int hw = (h << 6) + p;
#pragma unroll
      for (int r = 0; r < 4; ++r)
        out[(((bi << 8) + o + r) << 12) + hw] = acc[mf][nf][r] + bv[r];
    }
  }
}

extern "C" void kernel_launch(void* const* d_in, const int* in_sizes, int n_in,
                              void* d_out, int out_size, void* d_ws, size_t ws_size,
                              hipStream_t stream) {
  (void)in_sizes; (void)n_in; (void)out_size; (void)ws_size;
  const float* x        = (const float*)d_in[0];
  const float* w_offset = (const float*)d_in[1];
  const float* b_offset = (const float*)d_in[2];
  const float* w_mask   = (const float*)d_in[3];
  const float* b_mask   = (const float*)d_in[4];
  const float* weight   = (const float*)d_in[5];
  const float* bias     = (const float*)d_in[6];
  float* out = (float*)d_out;

  char* ws = (char*)d_ws;
  unsigned short* xt = (unsigned short*)(ws);
  __bf16* Wpack  = (__bf16*)(ws + 16777216);
  __bf16* Womp   = (__bf16*)(ws + 17956864);
  float*  dyp    = (float*)(ws + 18104320);
  float*  dxp    = (float*)(ws + 19283968);
  float*  mkp    = (float*)(ws + 20463616);

  transpose_nhwc<<<2048, 256, 0, stream>>>(x, xt);
  pack_w<<<2304, 256, 0, stream>>>(weight, Wpack);
  pack_wom<<<288, 256, 0, stream>>>(w_offset, w_mask, Womp);
  offset_conv<<<512, 256, 0, stream>>>(xt, Womp, b_offset, b_mask, dyp, dxp, mkp);
  deform_gemm<<<512, 512, 0, stream>>>(xt, Wpack, dyp, dxp, mkp, bias, out);
}

// Round 5
// 110.778 us; speedup vs baseline: 1.6543x; 1.0063x over previous
//
#include <hip/hip_runtime.h>
#include <math.h>

// DeformConv2dPack on MI355X (gfx950) — v5
// B=8, C=256, H=W=64, Cout=256, K=3x3, stride=1, pad=1, dil=1
//
// v5 changes vs v4:
//  - per-step __syncthreads() replaced by {s_waitcnt lgkmcnt(0); s_barrier}:
//    LDS-only drain. __syncthreads emits vmcnt(0) which force-drained the
//    prefetched gather loads at every barrier (T4/counted-vmcnt insight);
//    now global prefetch stays in flight across the barrier and is consumed
//    one full step later. Applied to deform_gemm and offset_conv.
//    Safety: dbuf + per-step lgkm(0) covers write-after-read across steps;
//    gathers are read-only so need no barrier ordering.
//
// ws layout:
//  [0)          xt bf16 NHWC   16,777,216 B
//  [16777216)   Wpack bf16      1,179,648 B
//  [17956864)   Womp bf16         147,456 B
//  [18104320)   dy fp32         1,179,648 B
//  [19283968)   dx fp32         1,179,648 B
//  [20463616)   mask fp32       1,179,648 B   (end 21,643,264)

typedef __bf16 bf16x8 __attribute__((ext_vector_type(8)));
typedef float  f32x4  __attribute__((ext_vector_type(4)));
typedef float  f32x2  __attribute__((ext_vector_type(2)));
typedef int    i32x4  __attribute__((ext_vector_type(4)));
typedef unsigned short u16x8 __attribute__((ext_vector_type(8)));
typedef unsigned short u16x4 __attribute__((ext_vector_type(4)));

__device__ __forceinline__ float b2f(unsigned short u) {
  return __builtin_bit_cast(float, ((unsigned)u) << 16);
}
__device__ __forceinline__ unsigned short f2b(float f) {
  return __builtin_bit_cast(unsigned short, (__bf16)f);
}
__device__ __forceinline__ float blo(unsigned u) {
  return __builtin_bit_cast(float, u << 16);
}
__device__ __forceinline__ float bhi(unsigned u) {
  return __builtin_bit_cast(float, u & 0xffff0000u);
}
// LDS-only barrier: drain LDS ops, keep global loads in flight.
__device__ __forceinline__ void lds_barrier() {
  asm volatile("s_waitcnt lgkmcnt(0)" ::: "memory");
  __builtin_amdgcn_s_barrier();
}

__global__ __launch_bounds__(256) void transpose_nhwc(const float* __restrict__ x,
                                                      unsigned short* __restrict__ xt) {
  __shared__ float tile[64][65];
  const int bid = blockIdx.x;
  const int b = bid & 7, rem = bid >> 3;
  const int cc = rem & 3, hw0 = (rem >> 2) << 6;
  const int t = threadIdx.x;
  const int a = t & 63, g = t >> 6;
#pragma unroll
  for (int r = 0; r < 16; ++r) {
    int crow = (r << 2) + g;
    tile[crow][a] = x[(((b << 8) + (cc << 6) + crow) << 12) + hw0 + a];
  }
  __syncthreads();
  const int a0 = (t & 15) << 2, gg = t >> 4;
#pragma unroll
  for (int r = 0; r < 4; ++r) {
    int hwr = (r << 4) + gg;
    u16x4 v;
#pragma unroll
    for (int j = 0; j < 4; ++j) v[j] = f2b(tile[a0 + j][hwr]);
    *(u16x4*)&xt[((b << 12) + hw0 + hwr) * 256 + (cc << 6) + a0] = v;
  }
}

__global__ __launch_bounds__(256) void pack_w(const float* __restrict__ w,
                                              __bf16* __restrict__ wp) {
  int idx = blockIdx.x * 256 + threadIdx.x;
  if (idx >= 256 * 256 * 9) return;
  int o = idx / 2304, rem = idx - o * 2304;
  int c = rem / 9, k = rem - c * 9;
  wp[(((k << 5) + (c >> 3)) * 256 + o) * 8 + (c & 7)] = (__bf16)w[idx];
}

__global__ __launch_bounds__(256) void pack_wom(const float* __restrict__ wo,
                                                const float* __restrict__ wm,
                                                __bf16* __restrict__ wp) {
  int idx = blockIdx.x * 256 + threadIdx.x;
  if (idx >= 32 * 256 * 9) return;
  int r = idx / 2304, rem = idx - r * 2304;
  int c = rem / 9, k = rem - c * 9;
  float v = 0.f;
  if (r < 18) v = wo[((r << 8) + c) * 9 + k];
  else if (r < 27) v = wm[(((r - 18) << 8) + c) * 9 + k];
  wp[(((k << 5) + (c >> 3)) * 32 + r) * 8 + (c & 7)] = (__bf16)v;
}

// K1: offset/mask conv. grid = 512 (bi = bid&7 XCD-swizzled, h = bid>>3), 256 thr.
__global__ __launch_bounds__(256) void offset_conv(
    const unsigned short* __restrict__ xt, const __bf16* __restrict__ wp,
    const float* __restrict__ b_off, const float* __restrict__ b_msk,
    float* __restrict__ dyp, float* __restrict__ dxp, float* __restrict__ mkp) {
  const int bi = blockIdx.x & 7, h = blockIdx.x >> 3;
  const int t = threadIdx.x, lane = t & 63, nw = t >> 6;
  const int l16 = lane & 15, lh = lane >> 4;
  __shared__ __align__(16) unsigned short S[2][64 * 72];
  f32x4 acc[2] = {};
  const int sp = t >> 2, sc0 = (t & 3) << 4;
  const long xb = (long)bi << 20;

  auto LOAD = [&](int it, u16x8* r) {
    const int k = it >> 2, cc = it & 3;
    const int hh = h + k / 3 - 1;
    const int ww = sp + k % 3 - 1;
    const bool valid = (hh >= 0) & (hh < 64) & (ww >= 0) & (ww < 64);
    if (valid) {
      const unsigned short* src = xt + xb + (((hh << 6) + ww) << 8) + (cc << 6) + sc0;
      r[0] = *(const u16x8*)src;
      r[1] = *(const u16x8*)(src + 8);
    } else {
      r[0] = u16x8{}; r[1] = u16x8{};
    }
  };

  auto STEP = [&](int it, const u16x8* r, int buf) {
    unsigned short* Sb = S[buf];
    *(u16x8*)&Sb[sp * 72 + sc0] = r[0];
    *(u16x8*)&Sb[sp * 72 + sc0 + 8] = r[1];
    lds_barrier();
    const int k = it >> 2, cc = it & 3;
#pragma unroll
    for (int kk = 0; kk < 2; ++kk) {
      const int prow = (nw << 4) + l16;
      bf16x8 bfrag = *(const bf16x8*)&Sb[prow * 72 + (kk << 5) + (lh << 3)];
#pragma unroll
      for (int mf = 0; mf < 2; ++mf) {
        const __bf16* ap = wp + ((((k << 5) + (cc << 3) + (kk << 2) + lh) << 5) + (mf << 4) + l16) * 8;
        bf16x8 af = *(const bf16x8*)ap;
        acc[mf] = __builtin_amdgcn_mfma_f32_16x16x32_bf16(af, bfrag, acc[mf], 0, 0, 0);
      }
    }
  };

  u16x8 rA[2], rB[2];
  LOAD(0, rA);
  for (int it = 0; it < 36; it += 2) {
    LOAD(it + 1, rB);
    STEP(it, rA, 0);
    if (it + 2 < 36) LOAD(it + 2, rA);
    STEP(it + 1, rB, 1);
  }

  const int p = (nw << 4) + l16;
  const int hw = (h << 6) + p;
#pragma unroll
  for (int mf = 0; mf < 2; ++mf) {
#pragma unroll
    for (int r = 0; r < 4; ++r) {
      int row = (mf << 4) + (lh << 2) + r;
      float v = acc[mf][r];
      if (row < 18) {
        v += b_off[row];
        float* dst = (row & 1) ? dxp : dyp;
        dst[(((bi * 9) + (row >> 1)) << 12) + hw] = v;
      } else if (row < 27) {
        int km = row - 18;
        v += b_msk[km];
        mkp[(((bi * 9) + km) << 12) + hw] = 1.f / (1.f + expf(-v));
      }
    }
  }
}

// K2: fused deformable-sample + GEMM. grid = 512 (bi = bid&7, h = bid>>3),
// 512 threads = 8 waves; wave wv owns out rows [wv*32, wv*32+32). Tile 256out x 64px.
__global__ __launch_bounds__(512, 4) void deform_gemm(
    const unsigned short* __restrict__ xt, const __bf16* __restrict__ wp,
    const float* __restrict__ dyp, const float* __restrict__ dxp,
    const float* __restrict__ mkp, const float* __restrict__ bias,
    float* __restrict__ out) {
  const int bi = blockIdx.x & 7, h = blockIdx.x >> 3;
  const int t = threadIdx.x, lane = t & 63, wv = t >> 6;
  const int l16 = lane & 15, lh = lane >> 4;
  __shared__ __align__(16) unsigned short S[2][64 * 72];  // 18.4 KB
  __shared__ __align__(16) float samp[9][64][8];          // 18 KB: w00..w11, o00..o11

  // Precompute per-(tap,px) interp weights + clamped corner offsets (once).
  for (int i = t; i < 576; i += 512) {
    int k = i >> 6, p = i & 63;
    int idx = (((bi * 9) + k) << 12) + (h << 6) + p;
    float dy = dyp[idx], dx = dxp[idx], mk = mkp[idx];
    float ys = (float)(h + k / 3 - 1) + dy;
    float xs = (float)(p + k % 3 - 1) + dx;
    float y0f = floorf(ys), x0f = floorf(xs);
    int iy0 = (int)y0f, ix0 = (int)x0f;
    float wy1 = ys - y0f, wx1 = xs - x0f;
    float wy0 = 1.f - wy1, wx0 = 1.f - wx1;
    float w00 = wy0 * wx0 * mk, w01 = wy0 * wx1 * mk;
    float w10 = wy1 * wx0 * mk, w11 = wy1 * wx1 * mk;
    if (iy0 < 0 || iy0 > 63) { w00 = 0.f; w01 = 0.f; }
    if (iy0 < -1 || iy0 > 62) { w10 = 0.f; w11 = 0.f; }
    if (ix0 < 0 || ix0 > 63) { w00 = 0.f; w10 = 0.f; }
    if (ix0 < -1 || ix0 > 62) { w01 = 0.f; w11 = 0.f; }
    const int cy0 = min(max(iy0, 0), 63), cy1 = min(max(iy0 + 1, 0), 63);
    const int cx0 = min(max(ix0, 0), 63), cx1 = min(max(ix0 + 1, 0), 63);
    samp[k][p][0] = w00; samp[k][p][1] = w01;
    samp[k][p][2] = w10; samp[k][p][3] = w11;
    samp[k][p][4] = __builtin_bit_cast(float, (((cy0 << 6) + cx0) << 8));
    samp[k][p][5] = __builtin_bit_cast(float, (((cy0 << 6) + cx1) << 8));
    samp[k][p][6] = __builtin_bit_cast(float, (((cy1 << 6) + cx0) << 8));
    samp[k][p][7] = __builtin_bit_cast(float, (((cy1 << 6) + cx1) << 8));
  }
  __syncthreads();

  f32x4 acc[2][4] = {};
  const int sp = t >> 3, sc0 = (t & 7) << 3;  // 8 thr/px, 8 ch each
  const unsigned short* xtb = xt + ((long)bi << 20);

  auto GATHER = [&](int it, u16x8* r, f32x4& w4) {
    const int k = it >> 2, cc = it & 3;
    w4 = *(const f32x4*)&samp[k][sp][0];
    i32x4 o4 = __builtin_bit_cast(i32x4, *(const f32x4*)&samp[k][sp][4]);
    const int c0 = (cc << 6) + sc0;
    r[0] = *(const u16x8*)(xtb + o4.x + c0);
    r[1] = *(const u16x8*)(xtb + o4.y + c0);
    r[2] = *(const u16x8*)(xtb + o4.z + c0);
    r[3] = *(const u16x8*)(xtb + o4.w + c0);
  };

  auto STEP = [&](int it, const u16x8* r, const f32x4& w4, int buf) {
    u16x8 sv;
    const unsigned* u0 = (const unsigned*)&r[0];
    const unsigned* u1 = (const unsigned*)&r[1];
    const unsigned* u2 = (const unsigned*)&r[2];
    const unsigned* u3 = (const unsigned*)&r[3];
#pragma unroll
    for (int j = 0; j < 4; ++j) {
      f32x2 a{blo(u0[j]), bhi(u0[j])};
      f32x2 b{blo(u1[j]), bhi(u1[j])};
      f32x2 c{blo(u2[j]), bhi(u2[j])};
      f32x2 d{blo(u3[j]), bhi(u3[j])};
      f32x2 s = a * w4.x;
      s += b * w4.y;
      s += c * w4.z;
      s += d * w4.w;
      sv[2 * j]     = f2b(s.x);
      sv[2 * j + 1] = f2b(s.y);
    }
    unsigned short* Sb = S[buf];
    *(u16x8*)&Sb[sp * 72 + sc0] = sv;
    lds_barrier();
    const int k = it >> 2, cc = it & 3;
#pragma unroll
    for (int kk = 0; kk < 2; ++kk) {
      bf16x8 bfr[4];
#pragma unroll
      for (int nf = 0; nf < 4; ++nf) {
        const int prow = (nf << 4) + l16;
        bfr[nf] = *(const bf16x8*)&Sb[prow * 72 + (kk << 5) + (lh << 3)];
      }
#pragma unroll
      for (int mf = 0; mf < 2; ++mf) {
        const int orow = (wv << 5) + (mf << 4) + l16;
        const __bf16* ap = wp + ((((k << 5) + (cc << 3) + (kk << 2) + lh) << 8) + orow) * 8;
        bf16x8 af = *(const bf16x8*)ap;
#pragma unroll
        for (int nf = 0; nf < 4; ++nf)
          acc[mf][nf] = __builtin_amdgcn_mfma_f32_16x16x32_bf16(af, bfr[nf], acc[mf][nf], 0, 0, 0);
      }
    }
  };

  u16x8 rA[4], rB[4];
  f32x4 wA, wB;
  GATHER(0, rA, wA);
  for (int it = 0; it < 36; it += 2) {
    GATHER(it + 1, rB, wB);
    STEP(it, rA, wA, 0);
    if (it + 2 < 36) GATHER(it + 2, rA, wA);
    STEP(it + 1, rB, wB, 1);
  }

#pragma unroll
  for (int mf = 0; mf < 2; ++mf) {
    const int o = (wv << 5) + (mf << 4) + (lh << 2);
    f32x4 bv = *(const f32x4*)(bias + o);
#pragma unroll
    for (int nf = 0; nf < 4; ++nf) {
      const int p = (nf << 4) + l16;
      const int hw = (h << 6) + p;
#pragma unroll
      for (int r = 0; r < 4; ++r)
        out[(((bi << 8) + o + r) << 12) + hw] = acc[mf][nf][r] + bv[r];
    }
  }
}

extern "C" void kernel_launch(void* const* d_in, const int* in_sizes, int n_in,
                              void* d_out, int out_size, void* d_ws, size_t ws_size,
                              hipStream_t stream) {
  (void)in_sizes; (void)n_in; (void)out_size; (void)ws_size;
  const float* x        = (const float*)d_in[0];
  const float* w_offset = (const float*)d_in[1];
  const float* b_offset = (const float*)d_in[2];
  const float* w_mask   = (const float*)d_in[3];
  const float* b_mask   = (const float*)d_in[4];
  const float* weight   = (const float*)d_in[5];
  const float* bias     = (const float*)d_in[6];
  float* out = (float*)d_out;

  char* ws = (char*)d_ws;
  unsigned short* xt = (unsigned short*)(ws);
  __bf16* Wpack  = (__bf16*)(ws + 16777216);
  __bf16* Womp   = (__bf16*)(ws + 17956864);
  float*  dyp    = (float*)(ws + 18104320);
  float*  dxp    = (float*)(ws + 19283968);
  float*  mkp    = (float*)(ws + 20463616);

  transpose_nhwc<<<2048, 256, 0, stream>>>(x, xt);
  pack_w<<<2304, 256, 0, stream>>>(weight, Wpack);
  pack_wom<<<288, 256, 0, stream>>>(w_offset, w_mask, Womp);
  offset_conv<<<512, 256, 0, stream>>>(xt, Womp, b_offset, b_mask, dyp, dxp, mkp);
  deform_gemm<<<512, 512, 0, stream>>>(xt, Wpack, dyp, dxp, mkp, bias, out);
}